// Round 7
// baseline (211.258 us; speedup 1.0000x reference)
//
#include <hip/hip_runtime.h>
#include <hip/hip_bf16.h>
#include <math.h>

#define NN 10000        // nodes
#define EIN 160000      // input edges
#define ETOT 170000     // + self loops
#define NG 64           // graphs
#define INDIM 128
#define HID 64
#define HEADS 8
#define D0 512          // HEADS*HID
#define OUTD 10

#define GBK 32
#define LPAD 8

using bfrag = __attribute__((ext_vector_type(8))) short;   // 8 bf16
using ffrag = __attribute__((ext_vector_type(4))) float;   // 4 f32

__device__ inline float bf2f(unsigned short u) { return __uint_as_float(((unsigned)u) << 16); }
__device__ inline unsigned short f2bf(float f) {
    __hip_bfloat16 b = __float2bfloat16(f);
    return *reinterpret_cast<unsigned short*>(&b);
}

// ---------------- fused prep: cast x + transpose-cast W0/W1/W2 + zero cnt ----------------
__device__ void transpose_tile(const float* __restrict__ src, __hip_bfloat16* __restrict__ dst,
                               int R, int C, int bx, int by) {
    __shared__ float tile[32][33];
    int cb = bx * 32, rb = by * 32;
    int tx = threadIdx.x & 31, ty = threadIdx.x >> 5; // 32 x 8
#pragma unroll
    for (int i = 0; i < 32; i += 8) {
        int r = rb + ty + i, c = cb + tx;
        tile[ty + i][tx] = (r < R && c < C) ? src[(size_t)r * C + c] : 0.f;
    }
    __syncthreads();
#pragma unroll
    for (int i = 0; i < 32; i += 8) {
        int c = cb + ty + i, r = rb + tx;
        if (c < C && r < R) dst[(size_t)c * R + r] = __float2bfloat16(tile[tx][ty + i]);
    }
}

// grid = 5000 (cast x) + 64 (W0) + 256 (W1) + 32 (W2) + 40 (zero cnt) = 5392
__global__ __launch_bounds__(256) void prep_kernel(const float* __restrict__ x,
                                                   const float* __restrict__ W0,
                                                   const float* __restrict__ W1,
                                                   const float* __restrict__ W2,
                                                   __hip_bfloat16* __restrict__ xb,
                                                   __hip_bfloat16* __restrict__ W0T,
                                                   __hip_bfloat16* __restrict__ W1T,
                                                   __hip_bfloat16* __restrict__ W2T,
                                                   int* __restrict__ cnt) {
    int bid = blockIdx.x;
    if (bid < 5000) {
        int i = bid * 256 + threadIdx.x;           // NN*INDIM = 1,280,000 = 5000*256 exactly
        xb[i] = __float2bfloat16(x[i]);
    } else if (bid < 5064) {
        int lb = bid - 5000;                       // W0: [128][512] -> [512][128], (16,4)
        transpose_tile(W0, W0T, INDIM, D0, lb & 15, lb >> 4);
    } else if (bid < 5320) {
        int lb = bid - 5064;                       // W1: [512][512] -> [512][512], (16,16)
        transpose_tile(W1, W1T, D0, D0, lb & 15, lb >> 4);
    } else if (bid < 5352) {
        int lb = bid - 5320;                       // W2: [512][64] -> [64][512], (2,16)
        transpose_tile(W2, W2T, D0, 64, lb & 1, lb >> 1);
    } else {
        int i = (bid - 5352) * 256 + threadIdx.x;
        if (i < NN) cnt[i] = 0;
    }
}

// ---------------- CSR build ----------------
__global__ void count_kernel(const int* __restrict__ ei, int* __restrict__ cnt) {
    int i = blockIdx.x * 256 + threadIdx.x;
    if (i >= ETOT) return;
    int dst = (i < EIN) ? ei[EIN + i] : (i - EIN);
    atomicAdd(&cnt[dst], 1);
}

__global__ __launch_bounds__(1024) void scan_kernel(const int* __restrict__ cnt,
                                                    int* __restrict__ row_ptr,
                                                    int* __restrict__ cursor) {
    __shared__ int ssum[1024];
    int t = threadIdx.x;
    const int PER = 10;
    int base = t * PER;
    int loc[PER];
    int s = 0;
#pragma unroll
    for (int i = 0; i < PER; i++) {
        int v = (base + i < NN) ? cnt[base + i] : 0;
        loc[i] = s; s += v;
    }
    ssum[t] = s;
    __syncthreads();
    for (int off = 1; off < 1024; off <<= 1) {
        int v = (t >= off) ? ssum[t - off] : 0;
        __syncthreads();
        ssum[t] += v;
        __syncthreads();
    }
    int bs = (t > 0) ? ssum[t - 1] : 0;
#pragma unroll
    for (int i = 0; i < PER; i++) {
        if (base + i < NN) { int v = bs + loc[i]; row_ptr[base + i] = v; cursor[base + i] = v; }
    }
    if (t == 0) row_ptr[NN] = ssum[1023];
}

__global__ void scatter_kernel(const int* __restrict__ ei, int* __restrict__ cursor,
                               int* __restrict__ col_src) {
    int i = blockIdx.x * 256 + threadIdx.x;
    if (i >= ETOT) return;
    int src, dst;
    if (i < EIN) { src = ei[i]; dst = ei[EIN + i]; }
    else { src = i - EIN; dst = src; }
    int pos = atomicAdd(&cursor[dst], 1);
    col_src[pos] = src;
}

// ---------------- bf16 MFMA GEMM + fused attention-dot epilogue ----------------
// C[M,N] = A[M,K] @ BT[N,K]^T. Tile = (32*FM) x 128, 4 waves (2x2), wave = (16*FM) x 64.
// Wave-half (wc) spans exactly one 64-col head.
template <int FM>
__global__ __launch_bounds__(256) void gemm_attn(const __hip_bfloat16* __restrict__ A,
                                                 const __hip_bfloat16* __restrict__ BT,
                                                 float* __restrict__ C,            // may be null
                                                 __hip_bfloat16* __restrict__ Cb,  // may be null
                                                 const float* __restrict__ asrc,   // [H,64]
                                                 const float* __restrict__ adst,   // [H,64]
                                                 float* __restrict__ a_s,          // [M,H]
                                                 float* __restrict__ a_d,          // [M,H]
                                                 int H, int M, int N, int K) {
    constexpr int TM = 32 * FM;
    __shared__ __align__(16) short As[TM][GBK + LPAD];
    __shared__ __align__(16) short Bs[128][GBK + LPAD];
    int tid = threadIdx.x;
    int wid = tid >> 6, lane = tid & 63;
    int wr = wid >> 1, wc = wid & 1;
    int brow = blockIdx.y * TM, bcol = blockIdx.x * 128;

    ffrag acc[FM][4] = {};

    int srow = tid >> 2;        // 0..63
    int skq  = (tid & 3) * 8;   // 0,8,16,24

    int kq = (lane >> 4) * 8;
    int ra = lane & 15;

    for (int k0 = 0; k0 < K; k0 += GBK) {
#pragma unroll
        for (int p = 0; p < TM / 64 || p == 0; ++p) {  // TM/64 passes (>=1)
            int r = srow + p * 64;
            if (r < TM) {
                int gr = brow + r;
                bfrag va = {0,0,0,0,0,0,0,0};
                if (gr < M) va = *(const bfrag*)(A + (size_t)gr * K + k0 + skq);
                *(bfrag*)&As[r][skq] = va;
            }
        }
#pragma unroll
        for (int p = 0; p < 2; ++p) {
            int r = srow + p * 64;
            int gc = bcol + r;
            bfrag vb = {0,0,0,0,0,0,0,0};
            if (gc < N) vb = *(const bfrag*)(BT + (size_t)gc * K + k0 + skq);
            *(bfrag*)&Bs[r][skq] = vb;
        }
        __syncthreads();
        bfrag af[FM], bf[4];
#pragma unroll
        for (int m = 0; m < FM; ++m) af[m] = *(const bfrag*)&As[wr * (16 * FM) + m * 16 + ra][kq];
#pragma unroll
        for (int n = 0; n < 4; ++n) bf[n] = *(const bfrag*)&Bs[wc * 64 + n * 16 + ra][kq];
#pragma unroll
        for (int m = 0; m < FM; ++m)
#pragma unroll
            for (int n = 0; n < 4; ++n)
                acc[m][n] = __builtin_amdgcn_mfma_f32_16x16x32_bf16(af[m], bf[n], acc[m][n], 0, 0, 0);
        __syncthreads();
    }

    int cr = (lane >> 4) * 4;
    int cc = lane & 15;

    // ---- C / Cb writes ----
#pragma unroll
    for (int m = 0; m < FM; ++m) {
#pragma unroll
        for (int n = 0; n < 4; ++n) {
#pragma unroll
            for (int r = 0; r < 4; ++r) {
                int grow = brow + wr * (16 * FM) + m * 16 + cr + r;
                int gcol = bcol + wc * 64 + n * 16 + cc;
                if (grow < M && gcol < N) {
                    float v = acc[m][n][r];
                    if (C)  C[(size_t)grow * N + gcol] = v;
                    if (Cb) Cb[(size_t)grow * N + gcol] = __float2bfloat16(v);
                }
            }
        }
    }

    // ---- fused attention dots ----
    int head = (bcol >> 6) + wc;
    if (head < H) {
        float asl[4], adl[4];
        int cbase = head * 64;
#pragma unroll
        for (int n = 0; n < 4; ++n) {
            asl[n] = asrc[cbase + n * 16 + cc];
            adl[n] = adst[cbase + n * 16 + cc];
        }
#pragma unroll
        for (int m = 0; m < FM; ++m) {
#pragma unroll
            for (int r = 0; r < 4; ++r) {
                float ps = 0.f, pd = 0.f;
#pragma unroll
                for (int n = 0; n < 4; ++n) {
                    float av = acc[m][n][r];
                    ps += av * asl[n];
                    pd += av * adl[n];
                }
#pragma unroll
                for (int o = 1; o < 16; o <<= 1) {
                    ps += __shfl_xor(ps, o);
                    pd += __shfl_xor(pd, o);
                }
                if (cc == 0) {
                    int row = brow + wr * (16 * FM) + m * 16 + cr + r;
                    if (row < M) {
                        a_s[(size_t)row * H + head] = ps;
                        a_d[(size_t)row * H + head] = pd;
                    }
                }
            }
        }
    }
}

// ---------------- GAT aggregate, 8 heads: 512 thr, 2 edge-parity groups ----------------
__global__ __launch_bounds__(512) void gat_agg8(const __hip_bfloat16* __restrict__ h,  // [N,512] bf16
                                                const float* __restrict__ a_s,          // [N,8]
                                                const float* __restrict__ a_d,          // [N,8]
                                                const int* __restrict__ row_ptr,
                                                const int* __restrict__ col_src,
                                                const float* __restrict__ bias,         // [512]
                                                __hip_bfloat16* __restrict__ out)       // [N,512] bf16 (relu)
{
    int n = blockIdx.x;
    int tid = threadIdx.x;
    int p = tid >> 8;             // edge parity group 0/1
    int t = tid & 255;
    int hh = t >> 5;              // head
    int c0 = t * 2;               // channels c0, c0+1
    int r0 = row_ptr[n], r1 = row_ptr[n + 1];
    float ad = a_d[n * 8 + hh];

    float acc0 = 0.f, acc1 = 0.f, ss = 0.f;
    const unsigned short* hu = (const unsigned short*)h;
    for (int k = r0 + p; k < r1; k += 16) {
        int kk[8]; int s[8]; float av[8]; unsigned v[8];
#pragma unroll
        for (int i = 0; i < 8; ++i) kk[i] = (k + 2 * i < r1) ? k + 2 * i : r1 - 1;
#pragma unroll
        for (int i = 0; i < 8; ++i) s[i] = col_src[kk[i]];
#pragma unroll
        for (int i = 0; i < 8; ++i) av[i] = a_s[s[i] * 8 + hh];
#pragma unroll
        for (int i = 0; i < 8; ++i) v[i] = *(const unsigned*)(hu + (size_t)s[i] * 512 + c0);
#pragma unroll
        for (int i = 0; i < 8; ++i) {
            float e = av[i] + ad;
            e = e > 0.f ? e : 0.2f * e;
            float al = __expf(e);
            al = (k + 2 * i < r1) ? al : 0.f;
            acc0 += al * bf2f((unsigned short)(v[i] & 0xffff));
            acc1 += al * bf2f((unsigned short)(v[i] >> 16));
            ss += al;
        }
    }
    __shared__ float sa0[2][256], sa1[2][256], sss[2][256];
    sa0[p][t] = acc0; sa1[p][t] = acc1; sss[p][t] = ss;
    __syncthreads();
    if (p == 0) {
        float A0 = acc0 + sa0[1][t];
        float A1 = acc1 + sa1[1][t];
        float S  = ss + sss[1][t];
        float inv = 1.f / (S + 1e-16f);
        float2 bv = *(const float2*)(bias + c0);
        float o0 = fmaxf(A0 * inv + bv.x, 0.f);
        float o1 = fmaxf(A1 * inv + bv.y, 0.f);
        unsigned pk = (unsigned)f2bf(o0) | ((unsigned)f2bf(o1) << 16);
        *(unsigned*)((unsigned short*)out + (size_t)n * 512 + c0) = pk;
    }
}

// ---------------- GAT aggregate, 1 head x 64 ch (layer 2): bf16 h, 2 groups ----------------
__global__ __launch_bounds__(512) void gat_agg1(const __hip_bfloat16* __restrict__ h,  // [N,64] bf16
                                                const float* __restrict__ a_s,  // [N]
                                                const float* __restrict__ a_d,  // [N]
                                                const int* __restrict__ row_ptr,
                                                const int* __restrict__ col_src,
                                                const float* __restrict__ bias, // [64]
                                                float* __restrict__ out) {      // [N,64] f32
    int tid = threadIdx.x;
    int nod = tid >> 7;                 // node slot 0..3
    int sub = tid & 127;
    int p = sub >> 6, lane = sub & 63;  // parity, channel
    int n = blockIdx.x * 4 + nod;
    __shared__ float sacc[4][2][64], sss[4][2][64];
    float acc = 0.f, ss = 0.f;
    int r0 = 0, r1 = 0;
    float ad = 0.f;
    if (n < NN) {
        r0 = row_ptr[n]; r1 = row_ptr[n + 1];
        ad = a_d[n];
        const unsigned short* hu = (const unsigned short*)h;
        for (int k = r0 + p; k < r1; k += 16) {
            int kk[8]; int s[8]; float av[8]; float v[8];
#pragma unroll
            for (int i = 0; i < 8; ++i) kk[i] = (k + 2 * i < r1) ? k + 2 * i : r1 - 1;
#pragma unroll
            for (int i = 0; i < 8; ++i) s[i] = col_src[kk[i]];
#pragma unroll
            for (int i = 0; i < 8; ++i) av[i] = a_s[s[i]];
#pragma unroll
            for (int i = 0; i < 8; ++i) v[i] = bf2f(hu[(size_t)s[i] * 64 + lane]);
#pragma unroll
            for (int i = 0; i < 8; ++i) {
                float e = av[i] + ad;
                e = e > 0.f ? e : 0.2f * e;
                float al = __expf(e);
                al = (k + 2 * i < r1) ? al : 0.f;
                acc += al * v[i];
                ss += al;
            }
        }
    }
    sacc[nod][p][lane] = acc; sss[nod][p][lane] = ss;
    __syncthreads();
    if (p == 0 && n < NN) {
        float A = acc + sacc[nod][1][lane];
        float S = ss + sss[nod][1][lane];
        out[(size_t)n * 64 + lane] = A / (S + 1e-16f) + bias[lane];
    }
}

// ---------------- fused pooling + classifier (batch is sorted) ----------------
__global__ __launch_bounds__(256) void pool_classify(const float* __restrict__ h,     // [N,64]
                                                     const int* __restrict__ batch,
                                                     const float* __restrict__ cW1, const float* __restrict__ cb1,
                                                     const float* __restrict__ cW2, const float* __restrict__ cb2,
                                                     float* __restrict__ out) {
    int g = blockIdx.x;
    int tid = threadIdx.x;
    int lane = tid & 63, w = tid >> 6;

    int lo = 0, hi = NN;
    while (lo < hi) { int mid = (lo + hi) >> 1; if (batch[mid] < g) lo = mid + 1; else hi = mid; }
    int s = lo;
    lo = s; hi = NN;
    while (lo < hi) { int mid = (lo + hi) >> 1; if (batch[mid] < g + 1) lo = mid + 1; else hi = mid; }
    int e = lo;

    float sum = 0.f, mx = -1e30f;
    for (int n = s + w; n < e; n += 4) {
        float v = h[(size_t)n * 64 + lane];
        sum += v; mx = fmaxf(mx, v);
    }
    __shared__ float ssum[4][64], smax[4][64];
    __shared__ float gv[128], c1[64];
    ssum[w][lane] = sum; smax[w][lane] = mx;
    __syncthreads();
    if (tid < 64) {
        float s4 = ssum[0][tid] + ssum[1][tid] + ssum[2][tid] + ssum[3][tid];
        float m4 = fmaxf(fmaxf(smax[0][tid], smax[1][tid]), fmaxf(smax[2][tid], smax[3][tid]));
        int cntv = e - s;
        float c = (float)(cntv > 1 ? cntv : 1);
        gv[tid] = s4 / c;
        gv[64 + tid] = m4;
    }
    __syncthreads();
    if (tid < 64) {
        float acc = cb1[tid];
        for (int k = 0; k < 128; k++) acc += gv[k] * cW1[k * 64 + tid];
        c1[tid] = fmaxf(acc, 0.f);
    }
    __syncthreads();
    if (tid < OUTD) {
        float o = cb2[tid];
        for (int k = 0; k < 64; k++) o += c1[k] * cW2[k * OUTD + tid];
        out[g * OUTD + tid] = o;
    }
}

// ---------------- launch ----------------
extern "C" void kernel_launch(void* const* d_in, const int* in_sizes, int n_in,
                              void* d_out, int out_size, void* d_ws, size_t ws_size,
                              hipStream_t stream) {
    const float* x     = (const float*)d_in[0];
    const int*   ei    = (const int*)d_in[1];
    const int*   batch = (const int*)d_in[2];
    const float* W0    = (const float*)d_in[3];
    const float* asrc0 = (const float*)d_in[4];
    const float* adst0 = (const float*)d_in[5];
    const float* b0    = (const float*)d_in[6];
    const float* W1    = (const float*)d_in[7];
    const float* asrc1 = (const float*)d_in[8];
    const float* adst1 = (const float*)d_in[9];
    const float* b1    = (const float*)d_in[10];
    const float* W2    = (const float*)d_in[11];
    const float* asrc2 = (const float*)d_in[12];
    const float* adst2 = (const float*)d_in[13];
    const float* b2    = (const float*)d_in[14];
    const float* cW1   = (const float*)d_in[15];
    const float* cb1   = (const float*)d_in[16];
    const float* cW2   = (const float*)d_in[17];
    const float* cb2   = (const float*)d_in[18];
    float* out = (float*)d_out;

    char* ws = (char*)d_ws;
    size_t off = 0;
    auto alloc = [&](size_t bytes) { void* p = ws + off; off += (bytes + 255) & ~(size_t)255; return p; };
    __hip_bfloat16* bufAb = (__hip_bfloat16*)alloc((size_t)NN * D0 * 2);  // bf16 GEMM out (gather src)
    __hip_bfloat16* bufBb = (__hip_bfloat16*)alloc((size_t)NN * D0 * 2);  // bf16 agg out
    __hip_bfloat16* bufCb = (__hip_bfloat16*)alloc((size_t)NN * 64 * 2);  // layer-2 GEMM out bf16
    float* bufD  = (float*)alloc((size_t)NN * 64 * 4);                    // layer-2 agg out f32
    __hip_bfloat16* xb   = (__hip_bfloat16*)alloc((size_t)NN * INDIM * 2);
    __hip_bfloat16* W0T  = (__hip_bfloat16*)alloc((size_t)D0 * INDIM * 2);
    __hip_bfloat16* W1T  = (__hip_bfloat16*)alloc((size_t)D0 * D0 * 2);
    __hip_bfloat16* W2T  = (__hip_bfloat16*)alloc((size_t)64 * D0 * 2);
    float* a_s     = (float*)alloc((size_t)NN * HEADS * 4);
    float* a_d     = (float*)alloc((size_t)NN * HEADS * 4);
    int*   cnt     = (int*)alloc((size_t)NN * 4);
    int*   row_ptr = (int*)alloc((size_t)(NN + 1) * 4);
    int*   cursor  = (int*)alloc((size_t)NN * 4);
    int*   col_src = (int*)alloc((size_t)(ETOT + 8) * 4);
    (void)ws_size; (void)n_in; (void)in_sizes; (void)out_size;

    // ---- prep: cast x + transpose weights + zero cnt (one dispatch) ----
    prep_kernel<<<5392, 256, 0, stream>>>(x, W0, W1, W2, xb, W0T, W1T, W2T, cnt);

    // ---- CSR build ----
    count_kernel<<<(ETOT + 255) / 256, 256, 0, stream>>>(ei, cnt);
    scan_kernel<<<1, 1024, 0, stream>>>(cnt, row_ptr, cursor);
    scatter_kernel<<<(ETOT + 255) / 256, 256, 0, stream>>>(ei, cursor, col_src);

    dim3 gg8(D0 / 128, (NN + 63) / 64);   // (4, 157)
    dim3 gg1(1, (NN + 63) / 64);          // (1, 157)

    // ---- layer 0 ----
    gemm_attn<2><<<gg8, 256, 0, stream>>>(xb, W0T, nullptr, bufAb, asrc0, adst0, a_s, a_d, HEADS, NN, D0, INDIM);
    gat_agg8<<<NN, 512, 0, stream>>>(bufAb, a_s, a_d, row_ptr, col_src, b0, bufBb);

    // ---- layer 1 ----
    gemm_attn<2><<<gg8, 256, 0, stream>>>(bufBb, W1T, nullptr, bufAb, asrc1, adst1, a_s, a_d, HEADS, NN, D0, D0);
    gat_agg8<<<NN, 512, 0, stream>>>(bufAb, a_s, a_d, row_ptr, col_src, b1, bufBb);

    // ---- layer 2 (1 head) ----
    gemm_attn<2><<<gg1, 256, 0, stream>>>(bufBb, W2T, nullptr, bufCb, asrc2, adst2, a_s, a_d, 1, NN, 64, D0);
    gat_agg1<<<(NN + 3) / 4, 512, 0, stream>>>(bufCb, a_s, a_d, row_ptr, col_src, b2, bufD);

    // ---- fused pooling + classifier ----
    pool_classify<<<NG, 256, 0, stream>>>(bufD, batch, cW1, cb1, cW2, cb2, out);
}

// Round 8
// 185.857 us; speedup vs baseline: 1.1367x; 1.1367x over previous
//
#include <hip/hip_runtime.h>
#include <hip/hip_bf16.h>
#include <math.h>

#define NN 10000        // nodes
#define EIN 160000      // input edges
#define ETOT 170000     // + self loops
#define NG 64           // graphs
#define INDIM 128
#define HID 64
#define HEADS 8
#define D0 512          // HEADS*HID
#define OUTD 10

using bfrag = __attribute__((ext_vector_type(8))) short;   // 8 bf16
using ffrag = __attribute__((ext_vector_type(4))) float;   // 4 f32

__device__ inline float bf2f(unsigned short u) { return __uint_as_float(((unsigned)u) << 16); }
__device__ inline unsigned short f2bf(float f) {
    __hip_bfloat16 b = __float2bfloat16(f);
    return *reinterpret_cast<unsigned short*>(&b);
}

// ---------------- fused prep: cast x + transpose-cast W0/W1/W2 + zero cnt ----------------
__device__ void transpose_tile(const float* __restrict__ src, __hip_bfloat16* __restrict__ dst,
                               int R, int C, int bx, int by) {
    __shared__ float tile[32][33];
    int cb = bx * 32, rb = by * 32;
    int tx = threadIdx.x & 31, ty = threadIdx.x >> 5; // 32 x 8
#pragma unroll
    for (int i = 0; i < 32; i += 8) {
        int r = rb + ty + i, c = cb + tx;
        tile[ty + i][tx] = (r < R && c < C) ? src[(size_t)r * C + c] : 0.f;
    }
    __syncthreads();
#pragma unroll
    for (int i = 0; i < 32; i += 8) {
        int c = cb + ty + i, r = rb + tx;
        if (c < C && r < R) dst[(size_t)c * R + r] = __float2bfloat16(tile[tx][ty + i]);
    }
}

// grid = 5000 (cast x) + 64 (W0) + 256 (W1) + 32 (W2) + 40 (zero cnt) = 5392
__global__ __launch_bounds__(256) void prep_kernel(const float* __restrict__ x,
                                                   const float* __restrict__ W0,
                                                   const float* __restrict__ W1,
                                                   const float* __restrict__ W2,
                                                   __hip_bfloat16* __restrict__ xb,
                                                   __hip_bfloat16* __restrict__ W0T,
                                                   __hip_bfloat16* __restrict__ W1T,
                                                   __hip_bfloat16* __restrict__ W2T,
                                                   int* __restrict__ cnt) {
    int bid = blockIdx.x;
    if (bid < 5000) {
        int i = bid * 256 + threadIdx.x;           // NN*INDIM = 1,280,000 = 5000*256 exactly
        xb[i] = __float2bfloat16(x[i]);
    } else if (bid < 5064) {
        int lb = bid - 5000;                       // W0: [128][512] -> [512][128], (16,4)
        transpose_tile(W0, W0T, INDIM, D0, lb & 15, lb >> 4);
    } else if (bid < 5320) {
        int lb = bid - 5064;                       // W1: [512][512] -> [512][512], (16,16)
        transpose_tile(W1, W1T, D0, D0, lb & 15, lb >> 4);
    } else if (bid < 5352) {
        int lb = bid - 5320;                       // W2: [512][64] -> [64][512], (2,16)
        transpose_tile(W2, W2T, D0, 64, lb & 1, lb >> 1);
    } else {
        int i = (bid - 5352) * 256 + threadIdx.x;
        if (i < NN) cnt[i] = 0;
    }
}

// ---------------- CSR build ----------------
__global__ void count_kernel(const int* __restrict__ ei, int* __restrict__ cnt) {
    int i = blockIdx.x * 256 + threadIdx.x;
    if (i >= ETOT) return;
    int dst = (i < EIN) ? ei[EIN + i] : (i - EIN);
    atomicAdd(&cnt[dst], 1);
}

__global__ __launch_bounds__(1024) void scan_kernel(const int* __restrict__ cnt,
                                                    int* __restrict__ row_ptr,
                                                    int* __restrict__ cursor) {
    __shared__ int ssum[1024];
    int t = threadIdx.x;
    const int PER = 10;
    int base = t * PER;
    int loc[PER];
    int s = 0;
#pragma unroll
    for (int i = 0; i < PER; i++) {
        int v = (base + i < NN) ? cnt[base + i] : 0;
        loc[i] = s; s += v;
    }
    ssum[t] = s;
    __syncthreads();
    for (int off = 1; off < 1024; off <<= 1) {
        int v = (t >= off) ? ssum[t - off] : 0;
        __syncthreads();
        ssum[t] += v;
        __syncthreads();
    }
    int bs = (t > 0) ? ssum[t - 1] : 0;
#pragma unroll
    for (int i = 0; i < PER; i++) {
        if (base + i < NN) { int v = bs + loc[i]; row_ptr[base + i] = v; cursor[base + i] = v; }
    }
    if (t == 0) row_ptr[NN] = ssum[1023];
}

__global__ void scatter_kernel(const int* __restrict__ ei, int* __restrict__ cursor,
                               int* __restrict__ col_src) {
    int i = blockIdx.x * 256 + threadIdx.x;
    if (i >= ETOT) return;
    int src, dst;
    if (i < EIN) { src = ei[i]; dst = ei[EIN + i]; }
    else { src = i - EIN; dst = src; }
    int pos = atomicAdd(&cursor[dst], 1);
    col_src[pos] = src;
}

// ---------------- bf16 MFMA GEMM + fused attention-dot epilogue (R6 structure) ----------------
#define GBM 128
#define GBN 128
#define GBK 32
#define LPAD 8

__global__ __launch_bounds__(256) void gemm_attn(const __hip_bfloat16* __restrict__ A,
                                                 const __hip_bfloat16* __restrict__ BT,
                                                 float* __restrict__ C,            // may be null
                                                 __hip_bfloat16* __restrict__ Cb,  // may be null
                                                 const float* __restrict__ asrc,   // [H,64]
                                                 const float* __restrict__ adst,   // [H,64]
                                                 float* __restrict__ a_s,          // [M,H]
                                                 float* __restrict__ a_d,          // [M,H]
                                                 int H, int M, int N, int K) {
    __shared__ __align__(16) short As[GBM][GBK + LPAD];
    __shared__ __align__(16) short Bs[GBN][GBK + LPAD];
    int tid = threadIdx.x;
    int wid = tid >> 6, lane = tid & 63;
    int wr = wid >> 1, wc = wid & 1;
    int brow = blockIdx.y * GBM, bcol = blockIdx.x * GBN;

    ffrag acc[4][4] = {};

    int srow = tid >> 2;        // 0..63
    int skq  = (tid & 3) * 8;   // 0,8,16,24

    int kq = (lane >> 4) * 8;
    int ra = lane & 15;

    for (int k0 = 0; k0 < K; k0 += GBK) {
#pragma unroll
        for (int p = 0; p < 2; ++p) {
            int r = srow + p * 64;
            int gr = brow + r;
            bfrag va = {0,0,0,0,0,0,0,0};
            if (gr < M) va = *(const bfrag*)(A + (size_t)gr * K + k0 + skq);
            *(bfrag*)&As[r][skq] = va;
            int gc = bcol + r;
            bfrag vb = {0,0,0,0,0,0,0,0};
            if (gc < N) vb = *(const bfrag*)(BT + (size_t)gc * K + k0 + skq);
            *(bfrag*)&Bs[r][skq] = vb;
        }
        __syncthreads();
        bfrag af[4], bf[4];
#pragma unroll
        for (int m = 0; m < 4; ++m) af[m] = *(const bfrag*)&As[wr * 64 + m * 16 + ra][kq];
#pragma unroll
        for (int n = 0; n < 4; ++n) bf[n] = *(const bfrag*)&Bs[wc * 64 + n * 16 + ra][kq];
#pragma unroll
        for (int m = 0; m < 4; ++m)
#pragma unroll
            for (int n = 0; n < 4; ++n)
                acc[m][n] = __builtin_amdgcn_mfma_f32_16x16x32_bf16(af[m], bf[n], acc[m][n], 0, 0, 0);
        __syncthreads();
    }

    int cr = (lane >> 4) * 4;
    int cc = lane & 15;

    // ---- C / Cb writes ----
#pragma unroll
    for (int m = 0; m < 4; ++m) {
#pragma unroll
        for (int n = 0; n < 4; ++n) {
#pragma unroll
            for (int r = 0; r < 4; ++r) {
                int grow = brow + wr * 64 + m * 16 + cr + r;
                int gcol = bcol + wc * 64 + n * 16 + cc;
                if (grow < M && gcol < N) {
                    float v = acc[m][n][r];
                    if (C)  C[(size_t)grow * N + gcol] = v;
                    if (Cb) Cb[(size_t)grow * N + gcol] = __float2bfloat16(v);
                }
            }
        }
    }

    // ---- fused attention dots: wave-half spans one 64-col head ----
    int head = (bcol >> 6) + wc;
    if (head < H) {
        float asl[4], adl[4];
        int cbase = head * 64;
#pragma unroll
        for (int n = 0; n < 4; ++n) {
            asl[n] = asrc[cbase + n * 16 + cc];
            adl[n] = adst[cbase + n * 16 + cc];
        }
#pragma unroll
        for (int m = 0; m < 4; ++m) {
#pragma unroll
            for (int r = 0; r < 4; ++r) {
                float ps = 0.f, pd = 0.f;
#pragma unroll
                for (int n = 0; n < 4; ++n) {
                    float av = acc[m][n][r];
                    ps += av * asl[n];
                    pd += av * adl[n];
                }
#pragma unroll
                for (int o = 1; o < 16; o <<= 1) {
                    ps += __shfl_xor(ps, o);
                    pd += __shfl_xor(pd, o);
                }
                if (cc == 0) {
                    int row = brow + wr * 64 + m * 16 + cr + r;
                    if (row < M) {
                        a_s[(size_t)row * H + head] = ps;
                        a_d[(size_t)row * H + head] = pd;
                    }
                }
            }
        }
    }
}

// ---------------- GAT aggregate, 8 heads: LDS-alpha (computed once per edge-head) ----------------
__global__ __launch_bounds__(256) void gat_agg8(const __hip_bfloat16* __restrict__ h,  // [N,512] bf16
                                                const float* __restrict__ a_s,          // [N,8]
                                                const float* __restrict__ a_d,          // [N,8]
                                                const int* __restrict__ row_ptr,
                                                const int* __restrict__ col_src,
                                                const float* __restrict__ bias,         // [512]
                                                __hip_bfloat16* __restrict__ out)       // [N,512] bf16 (relu)
{
    int n = blockIdx.x;
    int tid = threadIdx.x;
    int hh = tid >> 5;            // head for gather phase
    int c0 = tid * 2;             // channels c0, c0+1
    int r0 = row_ptr[n], r1 = row_ptr[n + 1];

    __shared__ float ad_sh[8];
    __shared__ float al_sh[32][8];   // alpha per (edge-in-batch, head)
    __shared__ int   src_sh[32];
    if (tid < 8) ad_sh[tid] = a_d[n * 8 + tid];

    float acc0 = 0.f, acc1 = 0.f, ss = 0.f;
    const unsigned short* hu = (const unsigned short*)h;

    for (int kb = r0; kb < r1; kb += 32) {
        __syncthreads();   // ad_sh ready (iter 0); al_sh/src_sh consumed (iter >0)
        // ---- phase A: thread (eb, h8) computes one alpha ----
        {
            int eb = tid >> 3, h8 = tid & 7;
            int k = kb + eb;
            int kc = (k < r1) ? k : r1 - 1;
            int s = col_src[kc];
            if (h8 == 0) src_sh[eb] = s;
            float e = a_s[s * 8 + h8] + ad_sh[h8];
            e = e > 0.f ? e : 0.2f * e;
            float al = __expf(e);
            al_sh[eb][h8] = (k < r1) ? al : 0.f;
        }
        __syncthreads();
        // ---- phase B: pure gather; sub-batches independent -> loads pipeline ----
        int nb = (r1 - kb < 32) ? (r1 - kb) : 32;
        for (int j = 0; j < nb; j += 8) {
            int s[8]; float al[8]; unsigned v[8];
#pragma unroll
            for (int i = 0; i < 8; ++i) s[i] = src_sh[j + i];
#pragma unroll
            for (int i = 0; i < 8; ++i) al[i] = al_sh[j + i][hh];
#pragma unroll
            for (int i = 0; i < 8; ++i) v[i] = *(const unsigned*)(hu + (size_t)s[i] * 512 + c0);
#pragma unroll
            for (int i = 0; i < 8; ++i) {
                acc0 += al[i] * bf2f((unsigned short)(v[i] & 0xffff));
                acc1 += al[i] * bf2f((unsigned short)(v[i] >> 16));
                ss += al[i];
            }
        }
    }
    float inv = 1.f / (ss + 1e-16f);
    float2 bv = *(const float2*)(bias + c0);
    float o0 = fmaxf(acc0 * inv + bv.x, 0.f);
    float o1 = fmaxf(acc1 * inv + bv.y, 0.f);
    unsigned pk = (unsigned)f2bf(o0) | ((unsigned)f2bf(o1) << 16);
    *(unsigned*)((unsigned short*)out + (size_t)n * 512 + c0) = pk;
}

// ---------------- GAT aggregate, 1 head x 64 ch (layer 2), inline alpha, f32 h ----------------
__global__ __launch_bounds__(256) void gat_agg1(const float* __restrict__ h,    // [N,64]
                                                const float* __restrict__ a_s,  // [N]
                                                const float* __restrict__ a_d,  // [N]
                                                const int* __restrict__ row_ptr,
                                                const int* __restrict__ col_src,
                                                const float* __restrict__ bias, // [64]
                                                float* __restrict__ out) {
    int n = blockIdx.x * 4 + (threadIdx.x >> 6);
    int lane = threadIdx.x & 63;
    if (n >= NN) return;
    int r0 = row_ptr[n], r1 = row_ptr[n + 1];
    float ad = a_d[n];
    float acc = 0.f, ssum = 0.f;
    for (int k = r0; k < r1; k += 8) {
        int kk[8]; int s[8]; float av[8]; float v[8];
#pragma unroll
        for (int i = 0; i < 8; ++i) kk[i] = (k + i < r1) ? k + i : r1 - 1;
#pragma unroll
        for (int i = 0; i < 8; ++i) s[i] = col_src[kk[i]];
#pragma unroll
        for (int i = 0; i < 8; ++i) av[i] = a_s[s[i]];
#pragma unroll
        for (int i = 0; i < 8; ++i) v[i] = h[(size_t)s[i] * 64 + lane];
#pragma unroll
        for (int i = 0; i < 8; ++i) {
            float e = av[i] + ad;
            e = e > 0.f ? e : 0.2f * e;
            float al = __expf(e);
            al = (k + i < r1) ? al : 0.f;
            acc += al * v[i];
            ssum += al;
        }
    }
    out[(size_t)n * 64 + lane] = acc / (ssum + 1e-16f) + bias[lane];
}

// ---------------- fused pooling + classifier (batch is sorted) ----------------
__global__ __launch_bounds__(256) void pool_classify(const float* __restrict__ h,     // [N,64]
                                                     const int* __restrict__ batch,
                                                     const float* __restrict__ cW1, const float* __restrict__ cb1,
                                                     const float* __restrict__ cW2, const float* __restrict__ cb2,
                                                     float* __restrict__ out) {
    int g = blockIdx.x;
    int tid = threadIdx.x;
    int lane = tid & 63, w = tid >> 6;

    int lo = 0, hi = NN;
    while (lo < hi) { int mid = (lo + hi) >> 1; if (batch[mid] < g) lo = mid + 1; else hi = mid; }
    int s = lo;
    lo = s; hi = NN;
    while (lo < hi) { int mid = (lo + hi) >> 1; if (batch[mid] < g + 1) lo = mid + 1; else hi = mid; }
    int e = lo;

    float sum = 0.f, mx = -1e30f;
    for (int n = s + w; n < e; n += 4) {
        float v = h[(size_t)n * 64 + lane];
        sum += v; mx = fmaxf(mx, v);
    }
    __shared__ float ssum[4][64], smax[4][64];
    __shared__ float gv[128], c1[64];
    ssum[w][lane] = sum; smax[w][lane] = mx;
    __syncthreads();
    if (tid < 64) {
        float s4 = ssum[0][tid] + ssum[1][tid] + ssum[2][tid] + ssum[3][tid];
        float m4 = fmaxf(fmaxf(smax[0][tid], smax[1][tid]), fmaxf(smax[2][tid], smax[3][tid]));
        int cntv = e - s;
        float c = (float)(cntv > 1 ? cntv : 1);
        gv[tid] = s4 / c;
        gv[64 + tid] = m4;
    }
    __syncthreads();
    if (tid < 64) {
        float acc = cb1[tid];
        for (int k = 0; k < 128; k++) acc += gv[k] * cW1[k * 64 + tid];
        c1[tid] = fmaxf(acc, 0.f);
    }
    __syncthreads();
    if (tid < OUTD) {
        float o = cb2[tid];
        for (int k = 0; k < 64; k++) o += c1[k] * cW2[k * OUTD + tid];
        out[g * OUTD + tid] = o;
    }
}

// ---------------- launch ----------------
extern "C" void kernel_launch(void* const* d_in, const int* in_sizes, int n_in,
                              void* d_out, int out_size, void* d_ws, size_t ws_size,
                              hipStream_t stream) {
    const float* x     = (const float*)d_in[0];
    const int*   ei    = (const int*)d_in[1];
    const int*   batch = (const int*)d_in[2];
    const float* W0    = (const float*)d_in[3];
    const float* asrc0 = (const float*)d_in[4];
    const float* adst0 = (const float*)d_in[5];
    const float* b0    = (const float*)d_in[6];
    const float* W1    = (const float*)d_in[7];
    const float* asrc1 = (const float*)d_in[8];
    const float* adst1 = (const float*)d_in[9];
    const float* b1    = (const float*)d_in[10];
    const float* W2    = (const float*)d_in[11];
    const float* asrc2 = (const float*)d_in[12];
    const float* adst2 = (const float*)d_in[13];
    const float* b2    = (const float*)d_in[14];
    const float* cW1   = (const float*)d_in[15];
    const float* cb1   = (const float*)d_in[16];
    const float* cW2   = (const float*)d_in[17];
    const float* cb2   = (const float*)d_in[18];
    float* out = (float*)d_out;

    char* ws = (char*)d_ws;
    size_t off = 0;
    auto alloc = [&](size_t bytes) { void* p = ws + off; off += (bytes + 255) & ~(size_t)255; return p; };
    __hip_bfloat16* bufAb = (__hip_bfloat16*)alloc((size_t)NN * D0 * 2);  // bf16 GEMM out (gather src)
    __hip_bfloat16* bufBb = (__hip_bfloat16*)alloc((size_t)NN * D0 * 2);  // bf16 agg out
    float* bufC  = (float*)alloc((size_t)NN * 64 * 4);                    // layer-2 GEMM out f32
    float* bufD  = (float*)alloc((size_t)NN * 64 * 4);                    // layer-2 agg out f32
    __hip_bfloat16* xb   = (__hip_bfloat16*)alloc((size_t)NN * INDIM * 2);
    __hip_bfloat16* W0T  = (__hip_bfloat16*)alloc((size_t)D0 * INDIM * 2);
    __hip_bfloat16* W1T  = (__hip_bfloat16*)alloc((size_t)D0 * D0 * 2);
    __hip_bfloat16* W2T  = (__hip_bfloat16*)alloc((size_t)64 * D0 * 2);
    float* a_s     = (float*)alloc((size_t)NN * HEADS * 4);
    float* a_d     = (float*)alloc((size_t)NN * HEADS * 4);
    int*   cnt     = (int*)alloc((size_t)NN * 4);
    int*   row_ptr = (int*)alloc((size_t)(NN + 1) * 4);
    int*   cursor  = (int*)alloc((size_t)NN * 4);
    int*   col_src = (int*)alloc((size_t)(ETOT + 8) * 4);
    (void)ws_size; (void)n_in; (void)in_sizes; (void)out_size;

    // ---- prep: cast x + transpose weights + zero cnt (one dispatch) ----
    prep_kernel<<<5392, 256, 0, stream>>>(x, W0, W1, W2, xb, W0T, W1T, W2T, cnt);

    // ---- CSR build ----
    count_kernel<<<(ETOT + 255) / 256, 256, 0, stream>>>(ei, cnt);
    scan_kernel<<<1, 1024, 0, stream>>>(cnt, row_ptr, cursor);
    scatter_kernel<<<(ETOT + 255) / 256, 256, 0, stream>>>(ei, cursor, col_src);

    dim3 gg8(D0 / GBN, (NN + GBM - 1) / GBM);   // (4, 79)
    dim3 gg1(1, (NN + GBM - 1) / GBM);          // (1, 79)

    // ---- layer 0 ----
    gemm_attn<<<gg8, 256, 0, stream>>>(xb, W0T, nullptr, bufAb, asrc0, adst0, a_s, a_d, HEADS, NN, D0, INDIM);
    gat_agg8<<<NN, 256, 0, stream>>>(bufAb, a_s, a_d, row_ptr, col_src, b0, bufBb);

    // ---- layer 1 ----
    gemm_attn<<<gg8, 256, 0, stream>>>(bufBb, W1T, nullptr, bufAb, asrc1, adst1, a_s, a_d, HEADS, NN, D0, D0);
    gat_agg8<<<NN, 256, 0, stream>>>(bufAb, a_s, a_d, row_ptr, col_src, b1, bufBb);

    // ---- layer 2 (1 head) ----
    gemm_attn<<<gg1, 256, 0, stream>>>(bufBb, W2T, bufC, nullptr, asrc2, adst2, a_s, a_d, 1, NN, 64, D0);
    gat_agg1<<<(NN + 3) / 4, 256, 0, stream>>>(bufC, a_s, a_d, row_ptr, col_src, b2, bufD);

    // ---- fused pooling + classifier ----
    pool_classify<<<NG, 256, 0, stream>>>(bufD, batch, cW1, cb1, cW2, cb2, out);
}

// Round 9
// 183.122 us; speedup vs baseline: 1.1537x; 1.0149x over previous
//
#include <hip/hip_runtime.h>
#include <hip/hip_bf16.h>
#include <math.h>

#define NN 10000        // nodes
#define EIN 160000      // input edges
#define ETOT 170000     // + self loops
#define NG 64           // graphs
#define INDIM 128
#define HID 64
#define HEADS 8
#define D0 512          // HEADS*HID
#define OUTD 10

using bfrag = __attribute__((ext_vector_type(8))) short;   // 8 bf16
using ffrag = __attribute__((ext_vector_type(4))) float;   // 4 f32
using u32x4 = __attribute__((ext_vector_type(4))) unsigned int;

__device__ inline float bf2f(unsigned short u) { return __uint_as_float(((unsigned)u) << 16); }
__device__ inline unsigned short f2bf(float f) {
    __hip_bfloat16 b = __float2bfloat16(f);
    return *reinterpret_cast<unsigned short*>(&b);
}

// ---------------- fused prep: cast x + transpose-cast W0/W1/W2 + zero cnt ----------------
__device__ void transpose_tile(const float* __restrict__ src, __hip_bfloat16* __restrict__ dst,
                               int R, int C, int bx, int by) {
    __shared__ float tile[32][33];
    int cb = bx * 32, rb = by * 32;
    int tx = threadIdx.x & 31, ty = threadIdx.x >> 5; // 32 x 8
#pragma unroll
    for (int i = 0; i < 32; i += 8) {
        int r = rb + ty + i, c = cb + tx;
        tile[ty + i][tx] = (r < R && c < C) ? src[(size_t)r * C + c] : 0.f;
    }
    __syncthreads();
#pragma unroll
    for (int i = 0; i < 32; i += 8) {
        int c = cb + ty + i, r = rb + tx;
        if (c < C && r < R) dst[(size_t)c * R + r] = __float2bfloat16(tile[tx][ty + i]);
    }
}

// grid = 5000 (cast x) + 64 (W0) + 256 (W1) + 32 (W2) + 40 (zero cnt) = 5392
__global__ __launch_bounds__(256) void prep_kernel(const float* __restrict__ x,
                                                   const float* __restrict__ W0,
                                                   const float* __restrict__ W1,
                                                   const float* __restrict__ W2,
                                                   __hip_bfloat16* __restrict__ xb,
                                                   __hip_bfloat16* __restrict__ W0T,
                                                   __hip_bfloat16* __restrict__ W1T,
                                                   __hip_bfloat16* __restrict__ W2T,
                                                   int* __restrict__ cnt) {
    int bid = blockIdx.x;
    if (bid < 5000) {
        int i = bid * 256 + threadIdx.x;           // NN*INDIM = 1,280,000 = 5000*256 exactly
        xb[i] = __float2bfloat16(x[i]);
    } else if (bid < 5064) {
        int lb = bid - 5000;                       // W0: [128][512] -> [512][128], (16,4)
        transpose_tile(W0, W0T, INDIM, D0, lb & 15, lb >> 4);
    } else if (bid < 5320) {
        int lb = bid - 5064;                       // W1: [512][512] -> [512][512], (16,16)
        transpose_tile(W1, W1T, D0, D0, lb & 15, lb >> 4);
    } else if (bid < 5352) {
        int lb = bid - 5320;                       // W2: [512][64] -> [64][512], (2,16)
        transpose_tile(W2, W2T, D0, 64, lb & 1, lb >> 1);
    } else {
        int i = (bid - 5352) * 256 + threadIdx.x;
        if (i < NN) cnt[i] = 0;
    }
}

// ---------------- CSR build ----------------
__global__ void count_kernel(const int* __restrict__ ei, int* __restrict__ cnt) {
    int i = blockIdx.x * 256 + threadIdx.x;
    if (i >= ETOT) return;
    int dst = (i < EIN) ? ei[EIN + i] : (i - EIN);
    atomicAdd(&cnt[dst], 1);
}

__global__ __launch_bounds__(1024) void scan_kernel(const int* __restrict__ cnt,
                                                    int* __restrict__ row_ptr,
                                                    int* __restrict__ cursor) {
    __shared__ int ssum[1024];
    int t = threadIdx.x;
    const int PER = 10;
    int base = t * PER;
    int loc[PER];
    int s = 0;
#pragma unroll
    for (int i = 0; i < PER; i++) {
        int v = (base + i < NN) ? cnt[base + i] : 0;
        loc[i] = s; s += v;
    }
    ssum[t] = s;
    __syncthreads();
    for (int off = 1; off < 1024; off <<= 1) {
        int v = (t >= off) ? ssum[t - off] : 0;
        __syncthreads();
        ssum[t] += v;
        __syncthreads();
    }
    int bs = (t > 0) ? ssum[t - 1] : 0;
#pragma unroll
    for (int i = 0; i < PER; i++) {
        if (base + i < NN) { int v = bs + loc[i]; row_ptr[base + i] = v; cursor[base + i] = v; }
    }
    if (t == 0) row_ptr[NN] = ssum[1023];
}

__global__ void scatter_kernel(const int* __restrict__ ei, int* __restrict__ cursor,
                               int* __restrict__ col_src) {
    int i = blockIdx.x * 256 + threadIdx.x;
    if (i >= ETOT) return;
    int src, dst;
    if (i < EIN) { src = ei[i]; dst = ei[EIN + i]; }
    else { src = i - EIN; dst = src; }
    int pos = atomicAdd(&cursor[dst], 1);
    col_src[pos] = src;
}

// ---------------- bf16 MFMA GEMM + fused attention-dot epilogue ----------------
#define GBM 128
#define GBN 128
#define GBK 32
#define LPAD 8

__global__ __launch_bounds__(256) void gemm_attn(const __hip_bfloat16* __restrict__ A,
                                                 const __hip_bfloat16* __restrict__ BT,
                                                 float* __restrict__ C,            // may be null
                                                 __hip_bfloat16* __restrict__ Cb,  // may be null
                                                 const float* __restrict__ asrc,   // [H,64]
                                                 const float* __restrict__ adst,   // [H,64]
                                                 float* __restrict__ a_s,          // [M,H]
                                                 float* __restrict__ a_d,          // [M,H]
                                                 int H, int M, int N, int K) {
    __shared__ __align__(16) short As[GBM][GBK + LPAD];
    __shared__ __align__(16) short Bs[GBN][GBK + LPAD];
    int tid = threadIdx.x;
    int wid = tid >> 6, lane = tid & 63;
    int wr = wid >> 1, wc = wid & 1;
    int brow = blockIdx.y * GBM, bcol = blockIdx.x * GBN;

    ffrag acc[4][4] = {};

    int srow = tid >> 2;        // 0..63
    int skq  = (tid & 3) * 8;   // 0,8,16,24

    int kq = (lane >> 4) * 8;
    int ra = lane & 15;

    for (int k0 = 0; k0 < K; k0 += GBK) {
#pragma unroll
        for (int p = 0; p < 2; ++p) {
            int r = srow + p * 64;
            int gr = brow + r;
            bfrag va = {0,0,0,0,0,0,0,0};
            if (gr < M) va = *(const bfrag*)(A + (size_t)gr * K + k0 + skq);
            *(bfrag*)&As[r][skq] = va;
            int gc = bcol + r;
            bfrag vb = {0,0,0,0,0,0,0,0};
            if (gc < N) vb = *(const bfrag*)(BT + (size_t)gc * K + k0 + skq);
            *(bfrag*)&Bs[r][skq] = vb;
        }
        __syncthreads();
        bfrag af[4], bf[4];
#pragma unroll
        for (int m = 0; m < 4; ++m) af[m] = *(const bfrag*)&As[wr * 64 + m * 16 + ra][kq];
#pragma unroll
        for (int n = 0; n < 4; ++n) bf[n] = *(const bfrag*)&Bs[wc * 64 + n * 16 + ra][kq];
#pragma unroll
        for (int m = 0; m < 4; ++m)
#pragma unroll
            for (int n = 0; n < 4; ++n)
                acc[m][n] = __builtin_amdgcn_mfma_f32_16x16x32_bf16(af[m], bf[n], acc[m][n], 0, 0, 0);
        __syncthreads();
    }

    int cr = (lane >> 4) * 4;
    int cc = lane & 15;

    // ---- C / Cb writes ----
#pragma unroll
    for (int m = 0; m < 4; ++m) {
#pragma unroll
        for (int n = 0; n < 4; ++n) {
#pragma unroll
            for (int r = 0; r < 4; ++r) {
                int grow = brow + wr * 64 + m * 16 + cr + r;
                int gcol = bcol + wc * 64 + n * 16 + cc;
                if (grow < M && gcol < N) {
                    float v = acc[m][n][r];
                    if (C)  C[(size_t)grow * N + gcol] = v;
                    if (Cb) Cb[(size_t)grow * N + gcol] = __float2bfloat16(v);
                }
            }
        }
    }

    // ---- fused attention dots: wave-half spans one 64-col head ----
    int head = (bcol >> 6) + wc;
    if (head < H) {
        float asl[4], adl[4];
        int cbase = head * 64;
#pragma unroll
        for (int n = 0; n < 4; ++n) {
            asl[n] = asrc[cbase + n * 16 + cc];
            adl[n] = adst[cbase + n * 16 + cc];
        }
#pragma unroll
        for (int m = 0; m < 4; ++m) {
#pragma unroll
            for (int r = 0; r < 4; ++r) {
                float ps = 0.f, pd = 0.f;
#pragma unroll
                for (int n = 0; n < 4; ++n) {
                    float av = acc[m][n][r];
                    ps += av * asl[n];
                    pd += av * adl[n];
                }
#pragma unroll
                for (int o = 1; o < 16; o <<= 1) {
                    ps += __shfl_xor(ps, o);
                    pd += __shfl_xor(pd, o);
                }
                if (cc == 0) {
                    int row = brow + wr * 64 + m * 16 + cr + r;
                    if (row < M) {
                        a_s[(size_t)row * H + head] = ps;
                        a_d[(size_t)row * H + head] = pd;
                    }
                }
            }
        }
    }
}

// ---------------- GAT aggregate, 8 heads: wave-per-node, 16B/lane gather ----------------
// lane covers channels lane*8 .. lane*8+7 (all in head = lane>>3).
// Per 8-edge batch: lane (j*8+h) computes alpha for (edge j, head h) once; shfl-broadcast.
__global__ __launch_bounds__(256) void gat_agg8(const __hip_bfloat16* __restrict__ h,  // [N,512] bf16
                                                const float* __restrict__ a_s,          // [N,8]
                                                const float* __restrict__ a_d,          // [N,8]
                                                const int* __restrict__ row_ptr,
                                                const int* __restrict__ col_src,
                                                const float* __restrict__ bias,         // [512]
                                                __hip_bfloat16* __restrict__ out)       // [N,512] bf16 (relu)
{
    int n = blockIdx.x * 4 + (threadIdx.x >> 6);   // grid 2500 * 4 waves = 10000 nodes
    int lane = threadIdx.x & 63;
    int r0 = row_ptr[n], r1 = row_ptr[n + 1];

    int head_c = lane & 7;                 // head this lane computes alpha for
    int hme = lane >> 3;                   // head of this lane's channels
    float ad_c = a_d[n * 8 + head_c];

    float acc[8] = {};
    float ss = 0.f;
    const unsigned short* hu = (const unsigned short*)h;

    for (int kb = r0; kb < r1; kb += 8) {
        // alpha role: edge slot = lane>>3, head = lane&7
        int k = kb + (lane >> 3);
        int kc = (k < r1) ? k : r1 - 1;
        int s_l = col_src[kc];
        float e = a_s[s_l * 8 + head_c] + ad_c;
        e = e > 0.f ? e : 0.2f * e;
        float al_l = (k < r1) ? __expf(e) : 0.f;
#pragma unroll
        for (int j = 0; j < 8; ++j) {
            int   sj = __shfl(s_l, j * 8);           // edge j's src (head-0 lane)
            float aj = __shfl(al_l, j * 8 + hme);    // alpha(edge j, my head)
            u32x4 v = *(const u32x4*)(hu + (size_t)sj * 512 + (lane << 3));
#pragma unroll
            for (int q = 0; q < 4; ++q) {
                acc[2 * q]     += aj * bf2f((unsigned short)(v[q] & 0xffff));
                acc[2 * q + 1] += aj * bf2f((unsigned short)(v[q] >> 16));
            }
            ss += aj;
        }
    }

    float inv = 1.f / (ss + 1e-16f);
    float4 b0v = *(const float4*)(bias + lane * 8);
    float4 b1v = *(const float4*)(bias + lane * 8 + 4);
    float ov[8];
    ov[0] = fmaxf(acc[0] * inv + b0v.x, 0.f);
    ov[1] = fmaxf(acc[1] * inv + b0v.y, 0.f);
    ov[2] = fmaxf(acc[2] * inv + b0v.z, 0.f);
    ov[3] = fmaxf(acc[3] * inv + b0v.w, 0.f);
    ov[4] = fmaxf(acc[4] * inv + b1v.x, 0.f);
    ov[5] = fmaxf(acc[5] * inv + b1v.y, 0.f);
    ov[6] = fmaxf(acc[6] * inv + b1v.z, 0.f);
    ov[7] = fmaxf(acc[7] * inv + b1v.w, 0.f);
    u32x4 pk;
#pragma unroll
    for (int q = 0; q < 4; ++q)
        pk[q] = (unsigned)f2bf(ov[2 * q]) | ((unsigned)f2bf(ov[2 * q + 1]) << 16);
    *(u32x4*)((unsigned short*)out + (size_t)n * 512 + (lane << 3)) = pk;
}

// ---------------- GAT aggregate, 1 head x 64 ch (layer 2), inline alpha, f32 h ----------------
__global__ __launch_bounds__(256) void gat_agg1(const float* __restrict__ h,    // [N,64]
                                                const float* __restrict__ a_s,  // [N]
                                                const float* __restrict__ a_d,  // [N]
                                                const int* __restrict__ row_ptr,
                                                const int* __restrict__ col_src,
                                                const float* __restrict__ bias, // [64]
                                                float* __restrict__ out) {
    int n = blockIdx.x * 4 + (threadIdx.x >> 6);
    int lane = threadIdx.x & 63;
    if (n >= NN) return;
    int r0 = row_ptr[n], r1 = row_ptr[n + 1];
    float ad = a_d[n];
    float acc = 0.f, ssum = 0.f;
    for (int k = r0; k < r1; k += 8) {
        int kk[8]; int s[8]; float av[8]; float v[8];
#pragma unroll
        for (int i = 0; i < 8; ++i) kk[i] = (k + i < r1) ? k + i : r1 - 1;
#pragma unroll
        for (int i = 0; i < 8; ++i) s[i] = col_src[kk[i]];
#pragma unroll
        for (int i = 0; i < 8; ++i) av[i] = a_s[s[i]];
#pragma unroll
        for (int i = 0; i < 8; ++i) v[i] = h[(size_t)s[i] * 64 + lane];
#pragma unroll
        for (int i = 0; i < 8; ++i) {
            float e = av[i] + ad;
            e = e > 0.f ? e : 0.2f * e;
            float al = __expf(e);
            al = (k + i < r1) ? al : 0.f;
            acc += al * v[i];
            ssum += al;
        }
    }
    out[(size_t)n * 64 + lane] = acc / (ssum + 1e-16f) + bias[lane];
}

// ---------------- fused pooling + classifier (batch is sorted) ----------------
__global__ __launch_bounds__(256) void pool_classify(const float* __restrict__ h,     // [N,64]
                                                     const int* __restrict__ batch,
                                                     const float* __restrict__ cW1, const float* __restrict__ cb1,
                                                     const float* __restrict__ cW2, const float* __restrict__ cb2,
                                                     float* __restrict__ out) {
    int g = blockIdx.x;
    int tid = threadIdx.x;
    int lane = tid & 63, w = tid >> 6;

    int lo = 0, hi = NN;
    while (lo < hi) { int mid = (lo + hi) >> 1; if (batch[mid] < g) lo = mid + 1; else hi = mid; }
    int s = lo;
    lo = s; hi = NN;
    while (lo < hi) { int mid = (lo + hi) >> 1; if (batch[mid] < g + 1) lo = mid + 1; else hi = mid; }
    int e = lo;

    float sum = 0.f, mx = -1e30f;
    for (int n = s + w; n < e; n += 4) {
        float v = h[(size_t)n * 64 + lane];
        sum += v; mx = fmaxf(mx, v);
    }
    __shared__ float ssum[4][64], smax[4][64];
    __shared__ float gv[128], c1[64];
    ssum[w][lane] = sum; smax[w][lane] = mx;
    __syncthreads();
    if (tid < 64) {
        float s4 = ssum[0][tid] + ssum[1][tid] + ssum[2][tid] + ssum[3][tid];
        float m4 = fmaxf(fmaxf(smax[0][tid], smax[1][tid]), fmaxf(smax[2][tid], smax[3][tid]));
        int cntv = e - s;
        float c = (float)(cntv > 1 ? cntv : 1);
        gv[tid] = s4 / c;
        gv[64 + tid] = m4;
    }
    __syncthreads();
    if (tid < 64) {
        float acc = cb1[tid];
        for (int k = 0; k < 128; k++) acc += gv[k] * cW1[k * 64 + tid];
        c1[tid] = fmaxf(acc, 0.f);
    }
    __syncthreads();
    if (tid < OUTD) {
        float o = cb2[tid];
        for (int k = 0; k < 64; k++) o += c1[k] * cW2[k * OUTD + tid];
        out[g * OUTD + tid] = o;
    }
}

// ---------------- launch ----------------
extern "C" void kernel_launch(void* const* d_in, const int* in_sizes, int n_in,
                              void* d_out, int out_size, void* d_ws, size_t ws_size,
                              hipStream_t stream) {
    const float* x     = (const float*)d_in[0];
    const int*   ei    = (const int*)d_in[1];
    const int*   batch = (const int*)d_in[2];
    const float* W0    = (const float*)d_in[3];
    const float* asrc0 = (const float*)d_in[4];
    const float* adst0 = (const float*)d_in[5];
    const float* b0    = (const float*)d_in[6];
    const float* W1    = (const float*)d_in[7];
    const float* asrc1 = (const float*)d_in[8];
    const float* adst1 = (const float*)d_in[9];
    const float* b1    = (const float*)d_in[10];
    const float* W2    = (const float*)d_in[11];
    const float* asrc2 = (const float*)d_in[12];
    const float* adst2 = (const float*)d_in[13];
    const float* b2    = (const float*)d_in[14];
    const float* cW1   = (const float*)d_in[15];
    const float* cb1   = (const float*)d_in[16];
    const float* cW2   = (const float*)d_in[17];
    const float* cb2   = (const float*)d_in[18];
    float* out = (float*)d_out;

    char* ws = (char*)d_ws;
    size_t off = 0;
    auto alloc = [&](size_t bytes) { void* p = ws + off; off += (bytes + 255) & ~(size_t)255; return p; };
    __hip_bfloat16* bufAb = (__hip_bfloat16*)alloc((size_t)NN * D0 * 2);  // bf16 GEMM out (gather src)
    __hip_bfloat16* bufBb = (__hip_bfloat16*)alloc((size_t)NN * D0 * 2);  // bf16 agg out
    float* bufC  = (float*)alloc((size_t)NN * 64 * 4);                    // layer-2 GEMM out f32
    float* bufD  = (float*)alloc((size_t)NN * 64 * 4);                    // layer-2 agg out f32
    __hip_bfloat16* xb   = (__hip_bfloat16*)alloc((size_t)NN * INDIM * 2);
    __hip_bfloat16* W0T  = (__hip_bfloat16*)alloc((size_t)D0 * INDIM * 2);
    __hip_bfloat16* W1T  = (__hip_bfloat16*)alloc((size_t)D0 * D0 * 2);
    __hip_bfloat16* W2T  = (__hip_bfloat16*)alloc((size_t)64 * D0 * 2);
    float* a_s     = (float*)alloc((size_t)NN * HEADS * 4);
    float* a_d     = (float*)alloc((size_t)NN * HEADS * 4);
    int*   cnt     = (int*)alloc((size_t)NN * 4);
    int*   row_ptr = (int*)alloc((size_t)(NN + 1) * 4);
    int*   cursor  = (int*)alloc((size_t)NN * 4);
    int*   col_src = (int*)alloc((size_t)(ETOT + 8) * 4);
    (void)ws_size; (void)n_in; (void)in_sizes; (void)out_size;

    // ---- prep: cast x + transpose weights + zero cnt (one dispatch) ----
    prep_kernel<<<5392, 256, 0, stream>>>(x, W0, W1, W2, xb, W0T, W1T, W2T, cnt);

    // ---- CSR build ----
    count_kernel<<<(ETOT + 255) / 256, 256, 0, stream>>>(ei, cnt);
    scan_kernel<<<1, 1024, 0, stream>>>(cnt, row_ptr, cursor);
    scatter_kernel<<<(ETOT + 255) / 256, 256, 0, stream>>>(ei, cursor, col_src);

    dim3 gg8(D0 / GBN, (NN + GBM - 1) / GBM);   // (4, 79)
    dim3 gg1(1, (NN + GBM - 1) / GBM);          // (1, 79)

    // ---- layer 0 ----
    gemm_attn<<<gg8, 256, 0, stream>>>(xb, W0T, nullptr, bufAb, asrc0, adst0, a_s, a_d, HEADS, NN, D0, INDIM);
    gat_agg8<<<2500, 256, 0, stream>>>(bufAb, a_s, a_d, row_ptr, col_src, b0, bufBb);

    // ---- layer 1 ----
    gemm_attn<<<gg8, 256, 0, stream>>>(bufBb, W1T, nullptr, bufAb, asrc1, adst1, a_s, a_d, HEADS, NN, D0, D0);
    gat_agg8<<<2500, 256, 0, stream>>>(bufAb, a_s, a_d, row_ptr, col_src, b1, bufBb);

    // ---- layer 2 (1 head) ----
    gemm_attn<<<gg1, 256, 0, stream>>>(bufBb, W2T, bufC, nullptr, asrc2, adst2, a_s, a_d, 1, NN, 64, D0);
    gat_agg1<<<(NN + 3) / 4, 256, 0, stream>>>(bufC, a_s, a_d, row_ptr, col_src, b2, bufD);

    // ---- fused pooling + classifier ----
    pool_classify<<<NG, 256, 0, stream>>>(bufD, batch, cW1, cb1, cW2, cb2, out);
}

// Round 10
// 169.795 us; speedup vs baseline: 1.2442x; 1.0785x over previous
//
#include <hip/hip_runtime.h>
#include <hip/hip_bf16.h>
#include <math.h>

#define NN 10000        // nodes
#define EIN 160000      // input edges
#define ETOT 170000     // + self loops
#define NG 64           // graphs
#define INDIM 128
#define HID 64
#define HEADS 8
#define D0 512          // HEADS*HID
#define OUTD 10

#define GBN 128
#define GBK 32
#define LPAD 8

using bfrag = __attribute__((ext_vector_type(8))) short;   // 8 bf16
using ffrag = __attribute__((ext_vector_type(4))) float;   // 4 f32
using u32x4 = __attribute__((ext_vector_type(4))) unsigned int;

__device__ inline float bf2f(unsigned short u) { return __uint_as_float(((unsigned)u) << 16); }
__device__ inline unsigned short f2bf(float f) {
    __hip_bfloat16 b = __float2bfloat16(f);
    return *reinterpret_cast<unsigned short*>(&b);
}

// ---------------- fused prep: cast x + transpose-cast W0/W1/W2 + zero cnt ----------------
__device__ void transpose_tile(const float* __restrict__ src, __hip_bfloat16* __restrict__ dst,
                               int R, int C, int bx, int by) {
    __shared__ float tile[32][33];
    int cb = bx * 32, rb = by * 32;
    int tx = threadIdx.x & 31, ty = threadIdx.x >> 5; // 32 x 8
#pragma unroll
    for (int i = 0; i < 32; i += 8) {
        int r = rb + ty + i, c = cb + tx;
        tile[ty + i][tx] = (r < R && c < C) ? src[(size_t)r * C + c] : 0.f;
    }
    __syncthreads();
#pragma unroll
    for (int i = 0; i < 32; i += 8) {
        int c = cb + ty + i, r = rb + tx;
        if (c < C && r < R) dst[(size_t)c * R + r] = __float2bfloat16(tile[tx][ty + i]);
    }
}

// grid = 5000 (cast x) + 64 (W0) + 256 (W1) + 32 (W2) + 40 (zero cnt) = 5392
__global__ __launch_bounds__(256) void prep_kernel(const float* __restrict__ x,
                                                   const float* __restrict__ W0,
                                                   const float* __restrict__ W1,
                                                   const float* __restrict__ W2,
                                                   __hip_bfloat16* __restrict__ xb,
                                                   __hip_bfloat16* __restrict__ W0T,
                                                   __hip_bfloat16* __restrict__ W1T,
                                                   __hip_bfloat16* __restrict__ W2T,
                                                   int* __restrict__ cnt) {
    int bid = blockIdx.x;
    if (bid < 5000) {
        int i = bid * 256 + threadIdx.x;           // NN*INDIM = 1,280,000 = 5000*256 exactly
        xb[i] = __float2bfloat16(x[i]);
    } else if (bid < 5064) {
        int lb = bid - 5000;                       // W0: [128][512] -> [512][128], (16,4)
        transpose_tile(W0, W0T, INDIM, D0, lb & 15, lb >> 4);
    } else if (bid < 5320) {
        int lb = bid - 5064;                       // W1: [512][512] -> [512][512], (16,16)
        transpose_tile(W1, W1T, D0, D0, lb & 15, lb >> 4);
    } else if (bid < 5352) {
        int lb = bid - 5320;                       // W2: [512][64] -> [64][512], (2,16)
        transpose_tile(W2, W2T, D0, 64, lb & 1, lb >> 1);
    } else {
        int i = (bid - 5352) * 256 + threadIdx.x;
        if (i < NN) cnt[i] = 0;
    }
}

// ---------------- CSR build ----------------
__global__ void count_kernel(const int* __restrict__ ei, int* __restrict__ cnt) {
    int i = blockIdx.x * 256 + threadIdx.x;
    if (i >= ETOT) return;
    int dst = (i < EIN) ? ei[EIN + i] : (i - EIN);
    atomicAdd(&cnt[dst], 1);
}

__global__ __launch_bounds__(1024) void scan_kernel(const int* __restrict__ cnt,
                                                    int* __restrict__ row_ptr,
                                                    int* __restrict__ cursor) {
    __shared__ int ssum[1024];
    int t = threadIdx.x;
    const int PER = 10;
    int base = t * PER;
    int loc[PER];
    int s = 0;
#pragma unroll
    for (int i = 0; i < PER; i++) {
        int v = (base + i < NN) ? cnt[base + i] : 0;
        loc[i] = s; s += v;
    }
    ssum[t] = s;
    __syncthreads();
    for (int off = 1; off < 1024; off <<= 1) {
        int v = (t >= off) ? ssum[t - off] : 0;
        __syncthreads();
        ssum[t] += v;
        __syncthreads();
    }
    int bs = (t > 0) ? ssum[t - 1] : 0;
#pragma unroll
    for (int i = 0; i < PER; i++) {
        if (base + i < NN) { int v = bs + loc[i]; row_ptr[base + i] = v; cursor[base + i] = v; }
    }
    if (t == 0) row_ptr[NN] = ssum[1023];
}

__global__ void scatter_kernel(const int* __restrict__ ei, int* __restrict__ cursor,
                               int* __restrict__ col_src) {
    int i = blockIdx.x * 256 + threadIdx.x;
    if (i >= ETOT) return;
    int src, dst;
    if (i < EIN) { src = ei[i]; dst = ei[EIN + i]; }
    else { src = i - EIN; dst = src; }
    int pos = atomicAdd(&cursor[dst], 1);
    col_src[pos] = src;
}

// ---------------- bf16 MFMA GEMM + fused attention-dot epilogue ----------------
// Tile (32*FM) x 128, 4 waves (2x2); wave covers (16*FM) rows x 64 cols (one head).
template <int FM>
__global__ __launch_bounds__(256) void gemm_attn(const __hip_bfloat16* __restrict__ A,
                                                 const __hip_bfloat16* __restrict__ BT,
                                                 float* __restrict__ C,            // may be null
                                                 __hip_bfloat16* __restrict__ Cb,  // may be null
                                                 const float* __restrict__ asrc,   // [H,64]
                                                 const float* __restrict__ adst,   // [H,64]
                                                 float* __restrict__ a_s,          // [M,H]
                                                 float* __restrict__ a_d,          // [M,H]
                                                 int H, int M, int N, int K) {
    constexpr int TM = 32 * FM;
    __shared__ __align__(16) short As[TM][GBK + LPAD];
    __shared__ __align__(16) short Bs[GBN][GBK + LPAD];
    int tid = threadIdx.x;
    int wid = tid >> 6, lane = tid & 63;
    int wr = wid >> 1, wc = wid & 1;
    int brow = blockIdx.y * TM, bcol = blockIdx.x * GBN;

    ffrag acc[FM][4] = {};

    int srow = tid >> 2;        // 0..63
    int skq  = (tid & 3) * 8;   // 0,8,16,24

    int kq = (lane >> 4) * 8;
    int ra = lane & 15;

    for (int k0 = 0; k0 < K; k0 += GBK) {
#pragma unroll
        for (int p = 0; p < FM / 2; ++p) {   // FM=2: 1 pass; FM=4: 2 passes
            int r = srow + p * 64;
            int gr = brow + r;
            bfrag va = {0,0,0,0,0,0,0,0};
            if (gr < M) va = *(const bfrag*)(A + (size_t)gr * K + k0 + skq);
            *(bfrag*)&As[r][skq] = va;
        }
#pragma unroll
        for (int p = 0; p < 2; ++p) {
            int r = srow + p * 64;
            int gc = bcol + r;
            bfrag vb = {0,0,0,0,0,0,0,0};
            if (gc < N) vb = *(const bfrag*)(BT + (size_t)gc * K + k0 + skq);
            *(bfrag*)&Bs[r][skq] = vb;
        }
        __syncthreads();
        bfrag af[FM], bf[4];
#pragma unroll
        for (int m = 0; m < FM; ++m) af[m] = *(const bfrag*)&As[wr * (16 * FM) + m * 16 + ra][kq];
#pragma unroll
        for (int n = 0; n < 4; ++n) bf[n] = *(const bfrag*)&Bs[wc * 64 + n * 16 + ra][kq];
#pragma unroll
        for (int m = 0; m < FM; ++m)
#pragma unroll
            for (int n = 0; n < 4; ++n)
                acc[m][n] = __builtin_amdgcn_mfma_f32_16x16x32_bf16(af[m], bf[n], acc[m][n], 0, 0, 0);
        __syncthreads();
    }

    int cr = (lane >> 4) * 4;
    int cc = lane & 15;

    // ---- C / Cb writes ----
#pragma unroll
    for (int m = 0; m < FM; ++m) {
#pragma unroll
        for (int n = 0; n < 4; ++n) {
#pragma unroll
            for (int r = 0; r < 4; ++r) {
                int grow = brow + wr * (16 * FM) + m * 16 + cr + r;
                int gcol = bcol + wc * 64 + n * 16 + cc;
                if (grow < M && gcol < N) {
                    float v = acc[m][n][r];
                    if (C)  C[(size_t)grow * N + gcol] = v;
                    if (Cb) Cb[(size_t)grow * N + gcol] = __float2bfloat16(v);
                }
            }
        }
    }

    // ---- fused attention dots: wave-half spans one 64-col head ----
    int head = (bcol >> 6) + wc;
    if (head < H) {
        float asl[4], adl[4];
        int cbase = head * 64;
#pragma unroll
        for (int n = 0; n < 4; ++n) {
            asl[n] = asrc[cbase + n * 16 + cc];
            adl[n] = adst[cbase + n * 16 + cc];
        }
#pragma unroll
        for (int m = 0; m < FM; ++m) {
#pragma unroll
            for (int r = 0; r < 4; ++r) {
                float ps = 0.f, pd = 0.f;
#pragma unroll
                for (int n = 0; n < 4; ++n) {
                    float av = acc[m][n][r];
                    ps += av * asl[n];
                    pd += av * adl[n];
                }
#pragma unroll
                for (int o = 1; o < 16; o <<= 1) {
                    ps += __shfl_xor(ps, o);
                    pd += __shfl_xor(pd, o);
                }
                if (cc == 0) {
                    int row = brow + wr * (16 * FM) + m * 16 + cr + r;
                    if (row < M) {
                        a_s[(size_t)row * H + head] = ps;
                        a_d[(size_t)row * H + head] = pd;
                    }
                }
            }
        }
    }
}

// ---------------- GAT aggregate, 8 heads: wave-per-node, 16B/lane, pipelined alpha ----------------
__global__ __launch_bounds__(256) void gat_agg8(const __hip_bfloat16* __restrict__ h,  // [N,512] bf16
                                                const float* __restrict__ a_s,          // [N,8]
                                                const float* __restrict__ a_d,          // [N,8]
                                                const int* __restrict__ row_ptr,
                                                const int* __restrict__ col_src,
                                                const float* __restrict__ bias,         // [512]
                                                __hip_bfloat16* __restrict__ out)       // [N,512] bf16 (relu)
{
    int n = blockIdx.x * 4 + (threadIdx.x >> 6);   // grid 2500 * 4 waves = 10000 nodes
    int lane = threadIdx.x & 63;
    int r0 = row_ptr[n], r1 = row_ptr[n + 1];

    int head_c = lane & 7;                 // head this lane computes alpha for
    int hme = lane >> 3;                   // head of this lane's channels
    float ad_c = a_d[n * 8 + head_c];

    float acc[8] = {};
    float ss = 0.f;
    const unsigned short* hu = (const unsigned short*)h;

    // prologue: alpha for batch at r0
    int k = r0 + (lane >> 3);
    int kc = (k < r1) ? k : r1 - 1;
    int s_l = col_src[kc];
    {
        float e = a_s[s_l * 8 + head_c] + ad_c;
        e = e > 0.f ? e : 0.2f * e;
        s_l = s_l;
    }
    float e0 = a_s[s_l * 8 + head_c] + ad_c;
    e0 = e0 > 0.f ? e0 : 0.2f * e0;
    float al_l = (k < r1) ? __expf(e0) : 0.f;

    for (int kb = r0; kb < r1; kb += 8) {
        int s_cur = s_l;
        float al_cur = al_l;
        int kb2 = kb + 8;
        bool more = kb2 < r1;
        int s_n = 0;
        if (more) {
            int k2 = kb2 + (lane >> 3);
            int kc2 = (k2 < r1) ? k2 : r1 - 1;
            s_n = col_src[kc2];               // issue next batch's index load early
        }
#pragma unroll
        for (int j = 0; j < 8; ++j) {
            int   sj = __shfl(s_cur, j * 8);           // edge j's src
            float aj = __shfl(al_cur, j * 8 + hme);    // alpha(edge j, my head)
            u32x4 v = *(const u32x4*)(hu + (size_t)sj * 512 + (lane << 3));
#pragma unroll
            for (int q = 0; q < 4; ++q) {
                acc[2 * q]     += aj * bf2f((unsigned short)(v[q] & 0xffff));
                acc[2 * q + 1] += aj * bf2f((unsigned short)(v[q] >> 16));
            }
            ss += aj;
        }
        if (more) {
            int k2 = kb2 + (lane >> 3);
            float e = a_s[s_n * 8 + head_c] + ad_c;
            e = e > 0.f ? e : 0.2f * e;
            al_l = (k2 < r1) ? __expf(e) : 0.f;
            s_l = s_n;
        }
    }

    float inv = 1.f / (ss + 1e-16f);
    float4 b0v = *(const float4*)(bias + lane * 8);
    float4 b1v = *(const float4*)(bias + lane * 8 + 4);
    float ov[8];
    ov[0] = fmaxf(acc[0] * inv + b0v.x, 0.f);
    ov[1] = fmaxf(acc[1] * inv + b0v.y, 0.f);
    ov[2] = fmaxf(acc[2] * inv + b0v.z, 0.f);
    ov[3] = fmaxf(acc[3] * inv + b0v.w, 0.f);
    ov[4] = fmaxf(acc[4] * inv + b1v.x, 0.f);
    ov[5] = fmaxf(acc[5] * inv + b1v.y, 0.f);
    ov[6] = fmaxf(acc[6] * inv + b1v.z, 0.f);
    ov[7] = fmaxf(acc[7] * inv + b1v.w, 0.f);
    u32x4 pk;
#pragma unroll
    for (int q = 0; q < 4; ++q)
        pk[q] = (unsigned)f2bf(ov[2 * q]) | ((unsigned)f2bf(ov[2 * q + 1]) << 16);
    *(u32x4*)((unsigned short*)out + (size_t)n * 512 + (lane << 3)) = pk;
}

// ---------------- GAT aggregate, 1 head x 64 ch (layer 2), inline alpha, f32 h ----------------
__global__ __launch_bounds__(256) void gat_agg1(const float* __restrict__ h,    // [N,64]
                                                const float* __restrict__ a_s,  // [N]
                                                const float* __restrict__ a_d,  // [N]
                                                const int* __restrict__ row_ptr,
                                                const int* __restrict__ col_src,
                                                const float* __restrict__ bias, // [64]
                                                float* __restrict__ out) {
    int n = blockIdx.x * 4 + (threadIdx.x >> 6);
    int lane = threadIdx.x & 63;
    if (n >= NN) return;
    int r0 = row_ptr[n], r1 = row_ptr[n + 1];
    float ad = a_d[n];
    float acc = 0.f, ssum = 0.f;
    for (int k = r0; k < r1; k += 8) {
        int kk[8]; int s[8]; float av[8]; float v[8];
#pragma unroll
        for (int i = 0; i < 8; ++i) kk[i] = (k + i < r1) ? k + i : r1 - 1;
#pragma unroll
        for (int i = 0; i < 8; ++i) s[i] = col_src[kk[i]];
#pragma unroll
        for (int i = 0; i < 8; ++i) av[i] = a_s[s[i]];
#pragma unroll
        for (int i = 0; i < 8; ++i) v[i] = h[(size_t)s[i] * 64 + lane];
#pragma unroll
        for (int i = 0; i < 8; ++i) {
            float e = av[i] + ad;
            e = e > 0.f ? e : 0.2f * e;
            float al = __expf(e);
            al = (k + i < r1) ? al : 0.f;
            acc += al * v[i];
            ssum += al;
        }
    }
    out[(size_t)n * 64 + lane] = acc / (ssum + 1e-16f) + bias[lane];
}

// ---------------- fused pooling + classifier (batch is sorted) ----------------
__global__ __launch_bounds__(256) void pool_classify(const float* __restrict__ h,     // [N,64]
                                                     const int* __restrict__ batch,
                                                     const float* __restrict__ cW1, const float* __restrict__ cb1,
                                                     const float* __restrict__ cW2, const float* __restrict__ cb2,
                                                     float* __restrict__ out) {
    int g = blockIdx.x;
    int tid = threadIdx.x;
    int lane = tid & 63, w = tid >> 6;

    int lo = 0, hi = NN;
    while (lo < hi) { int mid = (lo + hi) >> 1; if (batch[mid] < g) lo = mid + 1; else hi = mid; }
    int s = lo;
    lo = s; hi = NN;
    while (lo < hi) { int mid = (lo + hi) >> 1; if (batch[mid] < g + 1) lo = mid + 1; else hi = mid; }
    int e = lo;

    float sum = 0.f, mx = -1e30f;
    for (int n = s + w; n < e; n += 4) {
        float v = h[(size_t)n * 64 + lane];
        sum += v; mx = fmaxf(mx, v);
    }
    __shared__ float ssum[4][64], smax[4][64];
    __shared__ float gv[128], c1[64];
    ssum[w][lane] = sum; smax[w][lane] = mx;
    __syncthreads();
    if (tid < 64) {
        float s4 = ssum[0][tid] + ssum[1][tid] + ssum[2][tid] + ssum[3][tid];
        float m4 = fmaxf(fmaxf(smax[0][tid], smax[1][tid]), fmaxf(smax[2][tid], smax[3][tid]));
        int cntv = e - s;
        float c = (float)(cntv > 1 ? cntv : 1);
        gv[tid] = s4 / c;
        gv[64 + tid] = m4;
    }
    __syncthreads();
    if (tid < 64) {
        float acc = cb1[tid];
        for (int k = 0; k < 128; k++) acc += gv[k] * cW1[k * 64 + tid];
        c1[tid] = fmaxf(acc, 0.f);
    }
    __syncthreads();
    if (tid < OUTD) {
        float o = cb2[tid];
        for (int k = 0; k < 64; k++) o += c1[k] * cW2[k * OUTD + tid];
        out[g * OUTD + tid] = o;
    }
}

// ---------------- launch ----------------
extern "C" void kernel_launch(void* const* d_in, const int* in_sizes, int n_in,
                              void* d_out, int out_size, void* d_ws, size_t ws_size,
                              hipStream_t stream) {
    const float* x     = (const float*)d_in[0];
    const int*   ei    = (const int*)d_in[1];
    const int*   batch = (const int*)d_in[2];
    const float* W0    = (const float*)d_in[3];
    const float* asrc0 = (const float*)d_in[4];
    const float* adst0 = (const float*)d_in[5];
    const float* b0    = (const float*)d_in[6];
    const float* W1    = (const float*)d_in[7];
    const float* asrc1 = (const float*)d_in[8];
    const float* adst1 = (const float*)d_in[9];
    const float* b1    = (const float*)d_in[10];
    const float* W2    = (const float*)d_in[11];
    const float* asrc2 = (const float*)d_in[12];
    const float* adst2 = (const float*)d_in[13];
    const float* b2    = (const float*)d_in[14];
    const float* cW1   = (const float*)d_in[15];
    const float* cb1   = (const float*)d_in[16];
    const float* cW2   = (const float*)d_in[17];
    const float* cb2   = (const float*)d_in[18];
    float* out = (float*)d_out;

    char* ws = (char*)d_ws;
    size_t off = 0;
    auto alloc = [&](size_t bytes) { void* p = ws + off; off += (bytes + 255) & ~(size_t)255; return p; };
    __hip_bfloat16* bufAb = (__hip_bfloat16*)alloc((size_t)NN * D0 * 2);  // bf16 GEMM out (gather src)
    __hip_bfloat16* bufBb = (__hip_bfloat16*)alloc((size_t)NN * D0 * 2);  // bf16 agg out
    float* bufC  = (float*)alloc((size_t)NN * 64 * 4);                    // layer-2 GEMM out f32
    float* bufD  = (float*)alloc((size_t)NN * 64 * 4);                    // layer-2 agg out f32
    __hip_bfloat16* xb   = (__hip_bfloat16*)alloc((size_t)NN * INDIM * 2);
    __hip_bfloat16* W0T  = (__hip_bfloat16*)alloc((size_t)D0 * INDIM * 2);
    __hip_bfloat16* W1T  = (__hip_bfloat16*)alloc((size_t)D0 * D0 * 2);
    __hip_bfloat16* W2T  = (__hip_bfloat16*)alloc((size_t)64 * D0 * 2);
    float* a_s     = (float*)alloc((size_t)NN * HEADS * 4);
    float* a_d     = (float*)alloc((size_t)NN * HEADS * 4);
    int*   cnt     = (int*)alloc((size_t)NN * 4);
    int*   row_ptr = (int*)alloc((size_t)(NN + 1) * 4);
    int*   cursor  = (int*)alloc((size_t)NN * 4);
    int*   col_src = (int*)alloc((size_t)(ETOT + 8) * 4);
    (void)ws_size; (void)n_in; (void)in_sizes; (void)out_size;

    // ---- prep: cast x + transpose weights + zero cnt (one dispatch) ----
    prep_kernel<<<5392, 256, 0, stream>>>(x, W0, W1, W2, xb, W0T, W1T, W2T, cnt);

    // ---- CSR build ----
    count_kernel<<<(ETOT + 255) / 256, 256, 0, stream>>>(ei, cnt);
    scan_kernel<<<1, 1024, 0, stream>>>(cnt, row_ptr, cursor);
    scatter_kernel<<<(ETOT + 255) / 256, 256, 0, stream>>>(ei, cursor, col_src);

    dim3 gg8(D0 / GBN, (NN + 63) / 64);   // (4, 157)
    dim3 gg1(1, (NN + 63) / 64);          // (1, 157)

    // ---- layer 0 ----
    gemm_attn<2><<<gg8, 256, 0, stream>>>(xb, W0T, nullptr, bufAb, asrc0, adst0, a_s, a_d, HEADS, NN, D0, INDIM);
    gat_agg8<<<2500, 256, 0, stream>>>(bufAb, a_s, a_d, row_ptr, col_src, b0, bufBb);

    // ---- layer 1 ----
    gemm_attn<2><<<gg8, 256, 0, stream>>>(bufBb, W1T, nullptr, bufAb, asrc1, adst1, a_s, a_d, HEADS, NN, D0, D0);
    gat_agg8<<<2500, 256, 0, stream>>>(bufAb, a_s, a_d, row_ptr, col_src, b1, bufBb);

    // ---- layer 2 (1 head) ----
    gemm_attn<2><<<gg1, 256, 0, stream>>>(bufBb, W2T, bufC, nullptr, asrc2, adst2, a_s, a_d, 1, NN, 64, D0);
    gat_agg1<<<(NN + 3) / 4, 256, 0, stream>>>(bufC, a_s, a_d, row_ptr, col_src, b2, bufD);

    // ---- fused pooling + classifier ----
    pool_classify<<<NG, 256, 0, stream>>>(bufD, batch, cW1, cb1, cW2, cb2, out);
}